// Round 19
// baseline (67.058 us; speedup 1.0000x reference)
//
#include <hip/hip_runtime.h>
#include <hip/hip_bf16.h>

#define BB 8
#define NN 512
#define DINC 128
#define DOUTC 128
#define HHC 8
#define EEC 16
#define DHC 16

typedef _Float16 h4 __attribute__((ext_vector_type(4)));
typedef float f32x4 __attribute__((ext_vector_type(4)));

__device__ __forceinline__ float wsum(float v){
#pragma unroll
  for (int o=1;o<64;o<<=1) v += __shfl_xor(v,o);
  return v;
}

// ---------- one-shot weight swizzle (R17-verified): fragment-order f16 tables ----------
__global__ __launch_bounds__(256) void k_prep(
  const float* __restrict__ Wp, const float* __restrict__ Wq,
  const float* __restrict__ Wk, const float* __restrict__ Wv,
  const float* __restrict__ ffW1, const float* __restrict__ ffW2,
  const float* __restrict__ We1, const float* __restrict__ We2,
  _Float16* __restrict__ Wps, _Float16* __restrict__ Wqs,
  _Float16* __restrict__ Wks, _Float16* __restrict__ Wvs,
  _Float16* __restrict__ W1s, _Float16* __restrict__ W2s,
  _Float16* __restrict__ Wes)
{
  int id = blockIdx.x*256 + threadIdx.x;
  if (id < 32768){                       // ffW1: [ht<16][kt<8][lane][j]
    int j=id&3, lane=(id>>2)&63, kt=(id>>8)&7, ht=id>>11;
    int c=lane&15, g=lane>>4;
    W1s[id] = (_Float16)ffW1[(16*kt+4*g+j)*256 + 16*ht + c];
  } else if (id < 65536){                // ffW2: [ot<8][kt2<16][lane][j]
    int e=id-32768; int j=e&3, lane=(e>>2)&63, kt2=(e>>8)&15, ot=e>>12;
    int c=lane&15, g=lane>>4;
    W2s[e] = (_Float16)ffW2[(16*kt2+4*g+j)*128 + 16*ot + c];
  } else if (id < 131072){               // Wp/Wq/Wk/Wv: [ot<8][kt<8][lane][j]
    int e=id-65536; int sel=e>>14; e&=16383;
    int j=e&3, lane=(e>>2)&63, kt=(e>>8)&7, ot=e>>11;
    int c=lane&15, g=lane>>4;
    const float* W = (sel==0)?Wp:((sel==1)?Wq:((sel==2)?Wk:Wv));
    _Float16* D   = (sel==0)?Wps:((sel==1)?Wqs:((sel==2)?Wks:Wvs));
    D[e] = (_Float16)W[(16*kt+4*g+j)*128 + 16*ot + c];
  } else if (id < 132096){               // edge We1/We2 fragment tables (4x 256)
    int e=id-131072; int tbl=e>>8; int r=e&255;
    int lane=r>>2, j=r&3, c=lane&15, g=lane>>4;
    float v;
    if (tbl==0)      v = We1[(4*g+j)*32 + c];
    else if (tbl==1) v = We1[(4*g+j)*32 + 16 + c];
    else if (tbl==2) v = (c<8)? We2[(4*g+j)*HHC + c] : 0.f;
    else             v = (c<8)? We2[(16+4*g+j)*HHC + c] : 0.f;
    Wes[e] = (_Float16)v;
  }
}

// ---------- proj v3 (R17/R18-verified): swizzled-f16 weight loads ----------
__global__ __launch_bounds__(256) void k_proj(
    const float* __restrict__ x,
    const float* __restrict__ g1, const float* __restrict__ b1,
    const _Float16* __restrict__ Wps, const float* __restrict__ bp,
    const _Float16* __restrict__ Wqs, const _Float16* __restrict__ Wks, const _Float16* __restrict__ Wvs,
    float* __restrict__ xp, _Float16* __restrict__ Qh, _Float16* __restrict__ Kh, _Float16* __restrict__ Vh)
{
  __shared__ _Float16 xln[16][136];
  __shared__ _Float16 xps[16][136];
  __shared__ float    xp32[16][132];
  __shared__ _Float16 qs[3][16][136];
  int tid=threadIdx.x, w=tid>>6, lane=tid&63;
  int c=lane&15, g=lane>>4;
  int row0 = blockIdx.x*16;
  int b = row0>>9, n0 = row0&(NN-1);

  float ga=g1[lane], gb=g1[lane+64], ba=b1[lane], bbx=b1[lane+64];
#pragma unroll
  for (int rr=0;rr<4;++rr){
    int r = w + rr*4;
    size_t gi = (size_t)(row0+r)*DINC + lane;
    float a = x[gi], cc = x[gi+64];
    float s = wsum(a+cc);
    float q = wsum(a*a+cc*cc);
    float mean = s*(1.f/DINC);
    float var  = q*(1.f/DINC)-mean*mean;
    float rstd = rsqrtf(var+1e-5f);
    xln[r][lane]    = (_Float16)((a -mean)*rstd*ga + ba);
    xln[r][lane+64] = (_Float16)((cc-mean)*rstd*gb + bbx);
  }
  __syncthreads();

#pragma unroll
  for (int oo=0;oo<2;++oo){
    int ot = 2*w+oo;
    float4 bi = *(const float4*)(bp + 16*ot + 4*g);
    f32x4 D; D[0]=bi.x; D[1]=bi.y; D[2]=bi.z; D[3]=bi.w;
#pragma unroll
    for (int kt=0;kt<8;++kt){
      h4 f = *(const h4*)(Wps + (size_t)((ot*8+kt)*64 + lane)*4);
      h4 hb = *(const h4*)&xln[c][16*kt+4*g];
      D = __builtin_amdgcn_mfma_f32_16x16x16f16(f, hb, D, 0,0,0);
    }
#pragma unroll
    for (int r=0;r<4;++r){
      xp32[c][16*ot+4*g+r] = D[r];
      xps [c][16*ot+4*g+r] = (_Float16)D[r];
    }
  }
  __syncthreads();

#pragma unroll
  for (int pp=0;pp<6;++pp){
    int p = w + pp*4;
    int mat = p>>3, ot = p&7;
    const _Float16* W = (mat==0)? Wqs : ((mat==1)? Wks : Wvs);
    f32x4 D = {0.f,0.f,0.f,0.f};
#pragma unroll
    for (int kt=0;kt<8;++kt){
      h4 f = *(const h4*)(W + (size_t)((ot*8+kt)*64 + lane)*4);
      h4 hb = *(const h4*)&xps[c][16*kt+4*g];
      D = __builtin_amdgcn_mfma_f32_16x16x16f16(f, hb, D, 0,0,0);
    }
#pragma unroll
    for (int r=0;r<4;++r)
      qs[mat][c][16*ot+4*g+r] = (_Float16)D[r];
  }
  __syncthreads();

#pragma unroll
  for (int i=tid;i<512;i+=256){
    int r=i>>5, seg=i&31;
    *(float4*)(xp + (size_t)(row0+r)*DOUTC + seg*4) = *(const float4*)&xp32[r][seg*4];
  }
#pragma unroll
  for (int mat=0;mat<3;++mat){
    int r = tid>>4, seg = tid&15;
    int h = seg>>1, d = (seg&1)*8;
    _Float16* O = (mat==0)? Qh : ((mat==1)? Kh : Vh);
    *(float4*)(O + (((size_t)b*HHC+h)*NN + n0+r)*DHC + d) = *(const float4*)&qs[mat][r][seg*8];
  }
}

// ---------- edge-bias MLP v8: 2 rows/block (amortize fixed costs, 6% vs 20% tail) ----------
// Wave-pairs own one row each, 2-way tile striping. MLP math = R17/R18-verified.
__global__ __launch_bounds__(256) void k_edge(
  const float* __restrict__ ea, const int* __restrict__ adj,
  const float* __restrict__ eg, const float* __restrict__ ebi,
  const _Float16* __restrict__ Wes, const float* __restrict__ be1,
  const float* __restrict__ be2,
  _Float16* __restrict__ ebias)
{
  __shared__ _Float16 stage[2][8][520];       // 16.6KB
  __shared__ unsigned long long msk[2][8];
  __shared__ unsigned short idx16[2][512];    // 2KB

  int tid = threadIdx.x, w = tid>>6, lane = tid&63;
  int c = lane&15, g = lane>>4;
  int bp2 = blockIdx.x;                       // b*256 + pair
  int b = bp2 >> 8, pair = bp2 & 255;
  int nA = pair*2;

  // adjacency ballots for the 2 rows (keep per-thread bits for compaction)
  int vb00, vb01, vb10, vb11;
  {
    const int* adjRow = adj + ((size_t)b*NN + nA)*NN;
    vb00 = (adjRow[tid]     != 0) || (tid     == nA);
    vb01 = (adjRow[256+tid] != 0) || (256+tid == nA);
    unsigned long long m0 = __ballot(vb00);
    unsigned long long m1 = __ballot(vb01);
    if (lane==0){ msk[0][w] = m0; msk[0][4+w] = m1; }
  }
  {
    const int* adjRow = adj + ((size_t)b*NN + nA + 1)*NN;
    vb10 = (adjRow[tid]     != 0) || (tid     == nA+1);
    vb11 = (adjRow[256+tid] != 0) || (256+tid == nA+1);
    unsigned long long m0 = __ballot(vb10);
    unsigned long long m1 = __ballot(vb11);
    if (lane==0){ msk[1][w] = m0; msk[1][4+w] = m1; }
  }

  // fragment tables (R17): 4 coalesced 8B loads
  h4 w1a = *(const h4*)(Wes +        lane*4);
  h4 w1b = *(const h4*)(Wes + 256  + lane*4);
  h4 w2a = *(const h4*)(Wes + 512  + lane*4);
  h4 w2b = *(const h4*)(Wes + 768  + lane*4);
  float4 b1a = *(const float4*)(be1 + 4*g);
  float4 b1b = *(const float4*)(be1 + 16 + 4*g);
  float4 b2r = *(const float4*)(be2 + (g&1)*4);
  float4 G4  = *(const float4*)(eg  + 4*g);
  float4 Bv4 = *(const float4*)(ebi + 4*g);

  __syncthreads();

  // uniform prefix per row
  int offs0[8], offs1[8]; int cnt0=0, cnt1=0;
#pragma unroll
  for (int k=0;k<8;++k){ offs0[k]=cnt0; cnt0+=__popcll(msk[0][k]); }
#pragma unroll
  for (int k=0;k<8;++k){ offs1[k]=cnt1; cnt1+=__popcll(msk[1][k]); }

  { // prefill both stage rows with -30000, 16B writes
    _Float16 neg = (_Float16)(-30000.f);
    _Float16 nv8[8] = {neg,neg,neg,neg,neg,neg,neg,neg};
    float4 negv = *(const float4*)nv8;
#pragma unroll
    for (int i=tid;i<1024;i+=256){
      int r2 = i>>9, j = i&511;
      int h = j>>6, m8 = j&63;
      *(float4*)&stage[r2][h][m8*8] = negv;
    }
  }

  // compaction (4 chunks this thread touched)
  unsigned long long lm = (1ull<<lane)-1ull;
  if (vb00){ int pos = offs0[w]   + __popcll(msk[0][w]   & lm); idx16[0][pos] = (unsigned short)tid; }
  if (vb01){ int pos = offs0[4+w] + __popcll(msk[0][4+w] & lm); idx16[0][pos] = (unsigned short)(256+tid); }
  if (vb10){ int pos = offs1[w]   + __popcll(msk[1][w]   & lm); idx16[1][pos] = (unsigned short)tid; }
  if (vb11){ int pos = offs1[4+w] + __popcll(msk[1][4+w] & lm); idx16[1][pos] = (unsigned short)(256+tid); }
  __syncthreads();

  // MLP: wave-pair rr = w>>1 owns row nA+rr; 2-way tile striping within the pair
  int rr = w>>1, wi = w&1;
  int myCnt = rr ? cnt1 : cnt0;
  int nt = (myCnt + 15) >> 4;
  const float* eaRow = ea + ((size_t)b*NN + nA + rr)*NN*EEC;

  for (int t = wi; t < nt; t += 2){
    int slot = 16*t + c;
    int sidx = slot < myCnt ? slot : myCnt-1;
    int idx  = idx16[rr][sidx];
    float4 v = *(const float4*)(eaRow + (size_t)idx*EEC + 4*g);
    float s = v.x+v.y+v.z+v.w;
    float q = v.x*v.x+v.y*v.y+v.z*v.z+v.w*v.w;
    s += __shfl_xor(s,16); s += __shfl_xor(s,32);
    q += __shfl_xor(q,16); q += __shfl_xor(q,32);
    float mean = s*(1.f/EEC);
    float var  = q*(1.f/EEC) - mean*mean;
    float rstd = rsqrtf(var + 1e-5f);
    h4 ef;
    ef[0]=(_Float16)((v.x-mean)*rstd*G4.x + Bv4.x);
    ef[1]=(_Float16)((v.y-mean)*rstd*G4.y + Bv4.y);
    ef[2]=(_Float16)((v.z-mean)*rstd*G4.z + Bv4.z);
    ef[3]=(_Float16)((v.w-mean)*rstd*G4.w + Bv4.w);
    f32x4 d1a = {b1a.x,b1a.y,b1a.z,b1a.w};
    f32x4 d1b = {b1b.x,b1b.y,b1b.z,b1b.w};
    d1a = __builtin_amdgcn_mfma_f32_16x16x16f16(w1a, ef, d1a, 0,0,0);
    d1b = __builtin_amdgcn_mfma_f32_16x16x16f16(w1b, ef, d1b, 0,0,0);
    h4 hfa,hfb;
#pragma unroll
    for (int r=0;r<4;++r){
      hfa[r]=(_Float16)fmaxf(d1a[r],0.f);
      hfb[r]=(_Float16)fmaxf(d1b[r],0.f);
    }
    f32x4 d2 = {0.f,0.f,0.f,0.f};
    d2 = __builtin_amdgcn_mfma_f32_16x16x16f16(w2a, hfa, d2, 0,0,0);
    d2 = __builtin_amdgcn_mfma_f32_16x16x16f16(w2b, hfb, d2, 0,0,0);
    if (g<2 && slot<myCnt){
#pragma unroll
      for (int r=0;r<4;++r){
        float y = d2[r] + ((const float*)&b2r)[r];
        y = fminf(fmaxf(2.f*y,-30.f),30.f);
        float ex = __expf(y);
        float t2 = __fdividef(ex-1.f, ex+1.f);   // fast tanh ratio
        stage[rr][4*g+r][idx] = (_Float16)(5.f*t2);
      }
    }
  }
  __syncthreads();

  // coalesced writeout: 2 rows x 8 head planes x 1KB
  size_t base = ((size_t)b*HHC)*NN*NN + (size_t)nA*NN;
#pragma unroll
  for (int i=tid;i<1024;i+=256){
    int r2 = i>>9, j = i&511;
    int h = j>>6, m8 = j&63;
    *(float4*)(ebias + base + (size_t)h*NN*NN + (size_t)r2*NN + m8*8) =
        *(const float4*)&stage[r2][h][m8*8];
  }
}

// ---------- MFMA attention v3 (R16-R18-verified) ----------
__global__ __launch_bounds__(256) void k_attn(
  const _Float16* __restrict__ Qh, const _Float16* __restrict__ Kh, const _Float16* __restrict__ Vh,
  const _Float16* __restrict__ eb, float* __restrict__ ctxb)
{
  __shared__ _Float16 Vt[DHC*520];
  int tid = threadIdx.x;
  int bh   = blockIdx.x >> 3;
  int tile = blockIdx.x & 7;
  const _Float16* Vg = Vh + (size_t)bh*NN*DHC;
  {
#pragma unroll
    for (int i=tid;i<1024;i+=256){
      int m = i>>1, hf = i&1;
      float4 v4 = *(const float4*)(Vg + (size_t)m*DHC + hf*8);
      const _Float16* hh = (const _Float16*)&v4;
#pragma unroll
      for (int jj=0;jj<8;++jj) Vt[(hf*8+jj)*520 + m] = hh[jj];
    }
  }
  __syncthreads();

  int w = tid>>6, lane = tid&63;
  int c = lane&15, g = lane>>4;
  int n0 = tile*64 + w*16;

  h4 qf = *(const h4*)(Qh + ((size_t)bh*NN + n0 + c)*DHC + 4*g);
  const _Float16* ebw = eb + ((size_t)bh*NN + n0 + c)*NN + 4*g;
  const _Float16* Kb  = Kh + (size_t)bh*NN*DHC;

  f32x4 zero = {0.f,0.f,0.f,0.f};
  f32x4 acc = zero;
  float rowsum = 0.f;
#pragma unroll
  for (int t=0;t<32;++t){
    h4 kf = *(const h4*)(Kb + (size_t)(16*t + c)*DHC + 4*g);
    f32x4 d = __builtin_amdgcn_mfma_f32_16x16x16f16(kf, qf, zero, 0, 0, 0);
    h4 e4 = *(const h4*)(ebw + 16*t);
    h4 pa;
#pragma unroll
    for (int r=0;r<4;++r){
      float sv = d[r]*0.25f + (float)e4[r];
      sv = fmaxf(sv,0.f) + 0.2f*fminf(sv,0.f);
      float p = __expf(sv - 6.f);
      rowsum += p;
      pa[r] = (_Float16)p;
    }
    h4 vf = *(const h4*)(Vt + c*520 + 16*t + 4*g);
    acc = __builtin_amdgcn_mfma_f32_16x16x16f16(pa, vf, acc, 0, 0, 0);
  }
  rowsum += __shfl_xor(rowsum,16);
  rowsum += __shfl_xor(rowsum,32);

  int b = bh>>3, h = bh&7;
#pragma unroll
  for (int r=0;r<4;++r){
    float sr = __shfl(rowsum, g*16 + 4*g + r);
    ctxb[((size_t)b*NN + n0 + 4*g + r)*DOUTC + h*DHC + c] = acc[r]/sr;
  }
}

// ---------- FFN v6 (R18-verified) ----------
__global__ __launch_bounds__(256) void k_ffn(
  const float* __restrict__ xp, const float* __restrict__ ctxb,
  const float* __restrict__ g2, const float* __restrict__ b2v,
  const _Float16* __restrict__ W1s, const float* __restrict__ bb1,
  const _Float16* __restrict__ W2s, const float* __restrict__ bb2,
  float* __restrict__ out)
{
  __shared__ float    hrow[8][DOUTC];
  __shared__ _Float16 hn[16][136];
  __shared__ float    part[4][8][16][17];

  int tid = threadIdx.x, w = tid>>6, lane = tid&63;
  int c = lane&15, g = lane>>4;
  int n0 = blockIdx.x * 8;

#pragma unroll
  for (int i=tid;i<272;i+=256){
    h4 z = {(_Float16)0.f,(_Float16)0.f,(_Float16)0.f,(_Float16)0.f};
    ((h4*)hn)[272+i] = z;
  }

  float ga=g2[lane], gb=g2[lane+64], ba=b2v[lane], bbx=b2v[lane+64];
#pragma unroll
  for (int rr=0;rr<2;++rr){
    int r = w + rr*4;
    size_t gi = (size_t)(n0+r)*DOUTC + lane;
    float a  = xp[gi]    + ctxb[gi];
    float cc = xp[gi+64] + ctxb[gi+64];
    hrow[r][lane] = a; hrow[r][lane+64] = cc;
    float s = wsum(a+cc);
    float q = wsum(a*a+cc*cc);
    float mean = s*(1.f/DOUTC);
    float var  = q*(1.f/DOUTC) - mean*mean;
    float rstd = rsqrtf(var + 1e-5f);
    hn[r][lane]    = (_Float16)((a -mean)*rstd*ga + ba);
    hn[r][lane+64] = (_Float16)((cc-mean)*rstd*gb + bbx);
  }
  __syncthreads();

  h4 hidB[4];
#pragma unroll
  for (int t=0;t<4;++t){
    int ht = 4*w + t;
    float4 bi = *(const float4*)(bb1 + 16*ht + 4*g);
    f32x4 D1; D1[0]=bi.x; D1[1]=bi.y; D1[2]=bi.z; D1[3]=bi.w;
#pragma unroll
    for (int kt=0;kt<8;++kt){
      h4 f = *(const h4*)(W1s + (size_t)((ht*8+kt)*64 + lane)*4);
      h4 hb = *(const h4*)&hn[c][16*kt + 4*g];
      D1 = __builtin_amdgcn_mfma_f32_16x16x16f16(f, hb, D1, 0,0,0);
    }
#pragma unroll
    for (int r=0;r<4;++r) hidB[t][r] = (_Float16)fmaxf(D1[r], 0.f);
  }

#pragma unroll
  for (int ot=0;ot<8;++ot){
    f32x4 d2 = {0.f,0.f,0.f,0.f};
#pragma unroll
    for (int t=0;t<4;++t){
      h4 f = *(const h4*)(W2s + (size_t)((ot*16 + 4*w + t)*64 + lane)*4);
      d2 = __builtin_amdgcn_mfma_f32_16x16x16f16(f, hidB[t], d2, 0,0,0);
    }
#pragma unroll
    for (int r=0;r<4;++r) part[w][ot][4*g+r][c] = d2[r];
  }
  __syncthreads();

#pragma unroll
  for (int i=tid;i<1024;i+=256){
    int n = i>>7, col = i&127;
    int ot = col>>4, m = col&15;
    float v = part[0][ot][m][n] + part[1][ot][m][n]
            + part[2][ot][m][n] + part[3][ot][m][n];
    out[(size_t)(n0+n)*DOUTC + col] = hrow[n][col] + v + bb2[col];
  }
}

extern "C" void kernel_launch(void* const* d_in, const int* in_sizes, int n_in,
                              void* d_out, int out_size, void* d_ws, size_t ws_size,
                              hipStream_t stream)
{
  const float* x     = (const float*)d_in[0];
  const int*   adj   = (const int*)  d_in[1];
  const float* ea    = (const float*)d_in[2];
  const float* ln1_g = (const float*)d_in[3];
  const float* ln1_b = (const float*)d_in[4];
  const float* Wp    = (const float*)d_in[5];
  const float* bp    = (const float*)d_in[6];
  const float* eln_g = (const float*)d_in[7];
  const float* eln_b = (const float*)d_in[8];
  const float* We1   = (const float*)d_in[9];
  const float* be1   = (const float*)d_in[10];
  const float* We2   = (const float*)d_in[11];
  const float* be2   = (const float*)d_in[12];
  const float* Wq    = (const float*)d_in[13];
  const float* Wk    = (const float*)d_in[14];
  const float* Wv    = (const float*)d_in[15];
  const float* ffW1  = (const float*)d_in[16];
  const float* ffb1  = (const float*)d_in[17];
  const float* ffW2  = (const float*)d_in[18];
  const float* ffb2  = (const float*)d_in[19];
  const float* ln2_g = (const float*)d_in[20];
  const float* ln2_b = (const float*)d_in[21];
  float* out = (float*)d_out;

  char* ws = (char*)d_ws;
  float*    xp  = (float*)(ws);                       // 2MB (f32)
  float*    ctx = (float*)(ws + ((size_t)2<<20));     // 2MB
  _Float16* Qh  = (_Float16*)(ws + ((size_t)4<<20));  // 1MB
  _Float16* Kh  = (_Float16*)(ws + ((size_t)5<<20));  // 1MB
  _Float16* Vh  = (_Float16*)(ws + ((size_t)6<<20));  // 1MB
  _Float16* ebf = (_Float16*)(ws + ((size_t)7<<20));  // 32MB [B,H,N,N] f16
  char* wsw = ws + ((size_t)39<<20);                  // swizzled weights (258KB)
  _Float16* W1s = (_Float16*)(wsw);                   // 64KB
  _Float16* W2s = (_Float16*)(wsw + 65536);           // 64KB
  _Float16* Wps = (_Float16*)(wsw + 131072);          // 32KB
  _Float16* Wqs = (_Float16*)(wsw + 163840);          // 32KB
  _Float16* Wks = (_Float16*)(wsw + 196608);          // 32KB
  _Float16* Wvs = (_Float16*)(wsw + 229376);          // 32KB
  _Float16* Wes = (_Float16*)(wsw + 262144);          // 2KB

  k_prep<<<516, 256, 0, stream>>>(Wp, Wq, Wk, Wv, ffW1, ffW2, We1, We2,
                                  Wps, Wqs, Wks, Wvs, W1s, W2s, Wes);
  k_proj<<<(BB*NN)/16, 256, 0, stream>>>(x, ln1_g, ln1_b, Wps, bp, Wqs, Wks, Wvs, xp, Qh, Kh, Vh);
  k_edge<<<(BB*NN)/2, 256, 0, stream>>>(ea, adj, eln_g, eln_b, Wes, be1, be2, ebf);
  k_attn<<<BB*HHC*8, 256, 0, stream>>>(Qh, Kh, Vh, ebf, ctx);
  k_ffn<<<(BB*NN)/8, 256, 0, stream>>>(xp, ctx, ln2_g, ln2_b, W1s, ffb1, W2s, ffb2, out);
}

// Round 20
// 65.128 us; speedup vs baseline: 1.0296x; 1.0296x over previous
//
#include <hip/hip_runtime.h>
#include <hip/hip_bf16.h>

#define BB 8
#define NN 512
#define DINC 128
#define DOUTC 128
#define HHC 8
#define EEC 16
#define DHC 16

typedef _Float16 h4 __attribute__((ext_vector_type(4)));
typedef float f32x4 __attribute__((ext_vector_type(4)));

__device__ __forceinline__ float wsum(float v){
#pragma unroll
  for (int o=1;o<64;o<<=1) v += __shfl_xor(v,o);
  return v;
}

// ---------- one-shot weight swizzle (R17-verified): fragment-order f16 tables ----------
__global__ __launch_bounds__(256) void k_prep(
  const float* __restrict__ Wp, const float* __restrict__ Wq,
  const float* __restrict__ Wk, const float* __restrict__ Wv,
  const float* __restrict__ ffW1, const float* __restrict__ ffW2,
  const float* __restrict__ We1, const float* __restrict__ We2,
  _Float16* __restrict__ Wps, _Float16* __restrict__ Wqs,
  _Float16* __restrict__ Wks, _Float16* __restrict__ Wvs,
  _Float16* __restrict__ W1s, _Float16* __restrict__ W2s,
  _Float16* __restrict__ Wes)
{
  int id = blockIdx.x*256 + threadIdx.x;
  if (id < 32768){                       // ffW1: [ht<16][kt<8][lane][j]
    int j=id&3, lane=(id>>2)&63, kt=(id>>8)&7, ht=id>>11;
    int c=lane&15, g=lane>>4;
    W1s[id] = (_Float16)ffW1[(16*kt+4*g+j)*256 + 16*ht + c];
  } else if (id < 65536){                // ffW2: [ot<8][kt2<16][lane][j]
    int e=id-32768; int j=e&3, lane=(e>>2)&63, kt2=(e>>8)&15, ot=e>>12;
    int c=lane&15, g=lane>>4;
    W2s[e] = (_Float16)ffW2[(16*kt2+4*g+j)*128 + 16*ot + c];
  } else if (id < 131072){               // Wp/Wq/Wk/Wv: [ot<8][kt<8][lane][j]
    int e=id-65536; int sel=e>>14; e&=16383;
    int j=e&3, lane=(e>>2)&63, kt=(e>>8)&7, ot=e>>11;
    int c=lane&15, g=lane>>4;
    const float* W = (sel==0)?Wp:((sel==1)?Wq:((sel==2)?Wk:Wv));
    _Float16* D   = (sel==0)?Wps:((sel==1)?Wqs:((sel==2)?Wks:Wvs));
    D[e] = (_Float16)W[(16*kt+4*g+j)*128 + 16*ot + c];
  } else if (id < 132096){               // edge We1/We2 fragment tables (4x 256)
    int e=id-131072; int tbl=e>>8; int r=e&255;
    int lane=r>>2, j=r&3, c=lane&15, g=lane>>4;
    float v;
    if (tbl==0)      v = We1[(4*g+j)*32 + c];
    else if (tbl==1) v = We1[(4*g+j)*32 + 16 + c];
    else if (tbl==2) v = (c<8)? We2[(4*g+j)*HHC + c] : 0.f;
    else             v = (c<8)? We2[(16+4*g+j)*HHC + c] : 0.f;
    Wes[e] = (_Float16)v;
  }
}

// ---------- proj v3 (R17-verified): swizzled-f16 weight loads ----------
__global__ __launch_bounds__(256) void k_proj(
    const float* __restrict__ x,
    const float* __restrict__ g1, const float* __restrict__ b1,
    const _Float16* __restrict__ Wps, const float* __restrict__ bp,
    const _Float16* __restrict__ Wqs, const _Float16* __restrict__ Wks, const _Float16* __restrict__ Wvs,
    float* __restrict__ xp, _Float16* __restrict__ Qh, _Float16* __restrict__ Kh, _Float16* __restrict__ Vh)
{
  __shared__ _Float16 xln[16][136];
  __shared__ _Float16 xps[16][136];
  __shared__ float    xp32[16][132];
  __shared__ _Float16 qs[3][16][136];
  int tid=threadIdx.x, w=tid>>6, lane=tid&63;
  int c=lane&15, g=lane>>4;
  int row0 = blockIdx.x*16;
  int b = row0>>9, n0 = row0&(NN-1);

  float ga=g1[lane], gb=g1[lane+64], ba=b1[lane], bbx=b1[lane+64];
#pragma unroll
  for (int rr=0;rr<4;++rr){
    int r = w + rr*4;
    size_t gi = (size_t)(row0+r)*DINC + lane;
    float a = x[gi], cc = x[gi+64];
    float s = wsum(a+cc);
    float q = wsum(a*a+cc*cc);
    float mean = s*(1.f/DINC);
    float var  = q*(1.f/DINC)-mean*mean;
    float rstd = rsqrtf(var+1e-5f);
    xln[r][lane]    = (_Float16)((a -mean)*rstd*ga + ba);
    xln[r][lane+64] = (_Float16)((cc-mean)*rstd*gb + bbx);
  }
  __syncthreads();

#pragma unroll
  for (int oo=0;oo<2;++oo){
    int ot = 2*w+oo;
    float4 bi = *(const float4*)(bp + 16*ot + 4*g);
    f32x4 D; D[0]=bi.x; D[1]=bi.y; D[2]=bi.z; D[3]=bi.w;
#pragma unroll
    for (int kt=0;kt<8;++kt){
      h4 f = *(const h4*)(Wps + (size_t)((ot*8+kt)*64 + lane)*4);
      h4 hb = *(const h4*)&xln[c][16*kt+4*g];
      D = __builtin_amdgcn_mfma_f32_16x16x16f16(f, hb, D, 0,0,0);
    }
#pragma unroll
    for (int r=0;r<4;++r){
      xp32[c][16*ot+4*g+r] = D[r];
      xps [c][16*ot+4*g+r] = (_Float16)D[r];
    }
  }
  __syncthreads();

#pragma unroll
  for (int pp=0;pp<6;++pp){
    int p = w + pp*4;
    int mat = p>>3, ot = p&7;
    const _Float16* W = (mat==0)? Wqs : ((mat==1)? Wks : Wvs);
    f32x4 D = {0.f,0.f,0.f,0.f};
#pragma unroll
    for (int kt=0;kt<8;++kt){
      h4 f = *(const h4*)(W + (size_t)((ot*8+kt)*64 + lane)*4);
      h4 hb = *(const h4*)&xps[c][16*kt+4*g];
      D = __builtin_amdgcn_mfma_f32_16x16x16f16(f, hb, D, 0,0,0);
    }
#pragma unroll
    for (int r=0;r<4;++r)
      qs[mat][c][16*ot+4*g+r] = (_Float16)D[r];
  }
  __syncthreads();

#pragma unroll
  for (int i=tid;i<512;i+=256){
    int r=i>>5, seg=i&31;
    *(float4*)(xp + (size_t)(row0+r)*DOUTC + seg*4) = *(const float4*)&xp32[r][seg*4];
  }
#pragma unroll
  for (int mat=0;mat<3;++mat){
    int r = tid>>4, seg = tid&15;
    int h = seg>>1, d = (seg&1)*8;
    _Float16* O = (mat==0)? Qh : ((mat==1)? Kh : Vh);
    *(float4*)(O + (((size_t)b*HHC+h)*NN + n0+r)*DHC + d) = *(const float4*)&qs[mat][r][seg*8];
  }
}

// ---------- edge-bias MLP v7b (R17/R18-verified) ----------
__global__ __launch_bounds__(256) void k_edge(
  const float* __restrict__ ea, const int* __restrict__ adj,
  const float* __restrict__ eg, const float* __restrict__ ebi,
  const _Float16* __restrict__ Wes, const float* __restrict__ be1,
  const float* __restrict__ be2,
  _Float16* __restrict__ ebias)
{
  __shared__ _Float16 stage[8][520];
  __shared__ unsigned long long msk[8];
  __shared__ unsigned short idx16[512];
  __shared__ int cntS;

  int tid = threadIdx.x, w = tid>>6, lane = tid&63;
  int c = lane&15, g = lane>>4;
  int bn = blockIdx.x;
  int b = bn >> 9, n = bn & (NN-1);

  const int* adjRow = adj + (size_t)bn*NN;
  int col1 = tid, col2 = tid + 256;
  int v1 = (adjRow[col1] != 0) || (col1 == n);
  int v2 = (adjRow[col2] != 0) || (col2 == n);
  unsigned long long b1m = __ballot(v1);
  unsigned long long b2m = __ballot(v2);
  if (lane==0){ msk[w] = b1m; msk[4+w] = b2m; }

  h4 w1a = *(const h4*)(Wes +        lane*4);
  h4 w1b = *(const h4*)(Wes + 256  + lane*4);
  h4 w2a = *(const h4*)(Wes + 512  + lane*4);
  h4 w2b = *(const h4*)(Wes + 768  + lane*4);
  float4 b1a = *(const float4*)(be1 + 4*g);
  float4 b1b = *(const float4*)(be1 + 16 + 4*g);
  float4 b2r = *(const float4*)(be2 + (g&1)*4);
  float4 G4  = *(const float4*)(eg  + 4*g);
  float4 Bv4 = *(const float4*)(ebi + 4*g);

  __syncthreads();

  int offs[8]; int cnt = 0;
#pragma unroll
  for (int k=0;k<8;++k){ offs[k] = cnt; cnt += __popcll(msk[k]); }
  if (tid==0) cntS = cnt;

  {
    _Float16 neg = (_Float16)(-30000.f);
    _Float16 nv8[8] = {neg,neg,neg,neg,neg,neg,neg,neg};
    float4 negv = *(const float4*)nv8;
#pragma unroll
    for (int i=tid;i<512;i+=256){
      int h = i>>6, m8 = i&63;
      *(float4*)&stage[h][m8*8] = negv;
    }
  }

  if (v1){
    int pos = offs[w]   + __popcll(msk[w]   & ((1ull<<lane)-1ull));
    idx16[pos] = (unsigned short)col1;
  }
  if (v2){
    int pos = offs[4+w] + __popcll(msk[4+w] & ((1ull<<lane)-1ull));
    idx16[pos] = (unsigned short)col2;
  }
  __syncthreads();

  cnt = cntS;
  int nt = (cnt + 15) >> 4;
  const float* eaRow = ea + (size_t)bn*NN*EEC;

  for (int t = w; t < nt; t += 4){
    int slot = 16*t + c;
    int sidx = slot < cnt ? slot : cnt-1;
    int idx  = idx16[sidx];
    float4 v = *(const float4*)(eaRow + (size_t)idx*EEC + 4*g);
    float s = v.x+v.y+v.z+v.w;
    float q = v.x*v.x+v.y*v.y+v.z*v.z+v.w*v.w;
    s += __shfl_xor(s,16); s += __shfl_xor(s,32);
    q += __shfl_xor(q,16); q += __shfl_xor(q,32);
    float mean = s*(1.f/EEC);
    float var  = q*(1.f/EEC) - mean*mean;
    float rstd = rsqrtf(var + 1e-5f);
    h4 ef;
    ef[0]=(_Float16)((v.x-mean)*rstd*G4.x + Bv4.x);
    ef[1]=(_Float16)((v.y-mean)*rstd*G4.y + Bv4.y);
    ef[2]=(_Float16)((v.z-mean)*rstd*G4.z + Bv4.z);
    ef[3]=(_Float16)((v.w-mean)*rstd*G4.w + Bv4.w);
    f32x4 d1a = {b1a.x,b1a.y,b1a.z,b1a.w};
    f32x4 d1b = {b1b.x,b1b.y,b1b.z,b1b.w};
    d1a = __builtin_amdgcn_mfma_f32_16x16x16f16(w1a, ef, d1a, 0,0,0);
    d1b = __builtin_amdgcn_mfma_f32_16x16x16f16(w1b, ef, d1b, 0,0,0);
    h4 hfa,hfb;
#pragma unroll
    for (int r=0;r<4;++r){
      hfa[r]=(_Float16)fmaxf(d1a[r],0.f);
      hfb[r]=(_Float16)fmaxf(d1b[r],0.f);
    }
    f32x4 d2 = {0.f,0.f,0.f,0.f};
    d2 = __builtin_amdgcn_mfma_f32_16x16x16f16(w2a, hfa, d2, 0,0,0);
    d2 = __builtin_amdgcn_mfma_f32_16x16x16f16(w2b, hfb, d2, 0,0,0);
    if (g<2 && slot<cnt){
#pragma unroll
      for (int r=0;r<4;++r){
        float y = d2[r] + ((const float*)&b2r)[r];
        y = fminf(fmaxf(2.f*y,-30.f),30.f);
        float ex = __expf(y);
        float t2 = __fdividef(ex-1.f, ex+1.f);   // fast tanh ratio
        stage[4*g+r][idx] = (_Float16)(5.f*t2);
      }
    }
  }
  __syncthreads();

  size_t base = ((size_t)b*HHC)*NN*NN + (size_t)n*NN;
#pragma unroll
  for (int i=tid;i<512;i+=256){
    int h = i>>6, m8 = i&63;
    *(float4*)(ebias + base + (size_t)h*NN*NN + m8*8) =
        *(const float4*)&stage[h][m8*8];
  }
}

// ---------- MFMA attention v3 (R16-R18-verified) ----------
__global__ __launch_bounds__(256) void k_attn(
  const _Float16* __restrict__ Qh, const _Float16* __restrict__ Kh, const _Float16* __restrict__ Vh,
  const _Float16* __restrict__ eb, float* __restrict__ ctxb)
{
  __shared__ _Float16 Vt[DHC*520];
  int tid = threadIdx.x;
  int bh   = blockIdx.x >> 3;
  int tile = blockIdx.x & 7;
  const _Float16* Vg = Vh + (size_t)bh*NN*DHC;
  {
#pragma unroll
    for (int i=tid;i<1024;i+=256){
      int m = i>>1, hf = i&1;
      float4 v4 = *(const float4*)(Vg + (size_t)m*DHC + hf*8);
      const _Float16* hh = (const _Float16*)&v4;
#pragma unroll
      for (int jj=0;jj<8;++jj) Vt[(hf*8+jj)*520 + m] = hh[jj];
    }
  }
  __syncthreads();

  int w = tid>>6, lane = tid&63;
  int c = lane&15, g = lane>>4;
  int n0 = tile*64 + w*16;

  h4 qf = *(const h4*)(Qh + ((size_t)bh*NN + n0 + c)*DHC + 4*g);
  const _Float16* ebw = eb + ((size_t)bh*NN + n0 + c)*NN + 4*g;
  const _Float16* Kb  = Kh + (size_t)bh*NN*DHC;

  f32x4 zero = {0.f,0.f,0.f,0.f};
  f32x4 acc = zero;
  float rowsum = 0.f;
#pragma unroll
  for (int t=0;t<32;++t){
    h4 kf = *(const h4*)(Kb + (size_t)(16*t + c)*DHC + 4*g);
    f32x4 d = __builtin_amdgcn_mfma_f32_16x16x16f16(kf, qf, zero, 0, 0, 0);
    h4 e4 = *(const h4*)(ebw + 16*t);
    h4 pa;
#pragma unroll
    for (int r=0;r<4;++r){
      float sv = d[r]*0.25f + (float)e4[r];
      sv = fmaxf(sv,0.f) + 0.2f*fminf(sv,0.f);
      float p = __expf(sv - 6.f);
      rowsum += p;
      pa[r] = (_Float16)p;
    }
    h4 vf = *(const h4*)(Vt + c*520 + 16*t + 4*g);
    acc = __builtin_amdgcn_mfma_f32_16x16x16f16(pa, vf, acc, 0, 0, 0);
  }
  rowsum += __shfl_xor(rowsum,16);
  rowsum += __shfl_xor(rowsum,32);

  int b = bh>>3, h = bh&7;
#pragma unroll
  for (int r=0;r<4;++r){
    float sr = __shfl(rowsum, g*16 + 4*g + r);
    ctxb[((size_t)b*NN + n0 + 4*g + r)*DOUTC + h*DHC + c] = acc[r]/sr;
  }
}

// ---------- FFN v6 (R18-verified): part[] padded to 17 ----------
__global__ __launch_bounds__(256) void k_ffn(
  const float* __restrict__ xp, const float* __restrict__ ctxb,
  const float* __restrict__ g2, const float* __restrict__ b2v,
  const _Float16* __restrict__ W1s, const float* __restrict__ bb1,
  const _Float16* __restrict__ W2s, const float* __restrict__ bb2,
  float* __restrict__ out)
{
  __shared__ float    hrow[8][DOUTC];
  __shared__ _Float16 hn[16][136];
  __shared__ float    part[4][8][16][17];

  int tid = threadIdx.x, w = tid>>6, lane = tid&63;
  int c = lane&15, g = lane>>4;
  int n0 = blockIdx.x * 8;

#pragma unroll
  for (int i=tid;i<272;i+=256){
    h4 z = {(_Float16)0.f,(_Float16)0.f,(_Float16)0.f,(_Float16)0.f};
    ((h4*)hn)[272+i] = z;
  }

  float ga=g2[lane], gb=g2[lane+64], ba=b2v[lane], bbx=b2v[lane+64];
#pragma unroll
  for (int rr=0;rr<2;++rr){
    int r = w + rr*4;
    size_t gi = (size_t)(n0+r)*DOUTC + lane;
    float a  = xp[gi]    + ctxb[gi];
    float cc = xp[gi+64] + ctxb[gi+64];
    hrow[r][lane] = a; hrow[r][lane+64] = cc;
    float s = wsum(a+cc);
    float q = wsum(a*a+cc*cc);
    float mean = s*(1.f/DOUTC);
    float var  = q*(1.f/DOUTC) - mean*mean;
    float rstd = rsqrtf(var + 1e-5f);
    hn[r][lane]    = (_Float16)((a -mean)*rstd*ga + ba);
    hn[r][lane+64] = (_Float16)((cc-mean)*rstd*gb + bbx);
  }
  __syncthreads();

  h4 hidB[4];
#pragma unroll
  for (int t=0;t<4;++t){
    int ht = 4*w + t;
    float4 bi = *(const float4*)(bb1 + 16*ht + 4*g);
    f32x4 D1; D1[0]=bi.x; D1[1]=bi.y; D1[2]=bi.z; D1[3]=bi.w;
#pragma unroll
    for (int kt=0;kt<8;++kt){
      h4 f = *(const h4*)(W1s + (size_t)((ht*8+kt)*64 + lane)*4);
      h4 hb = *(const h4*)&hn[c][16*kt + 4*g];
      D1 = __builtin_amdgcn_mfma_f32_16x16x16f16(f, hb, D1, 0,0,0);
    }
#pragma unroll
    for (int r=0;r<4;++r) hidB[t][r] = (_Float16)fmaxf(D1[r], 0.f);
  }

#pragma unroll
  for (int ot=0;ot<8;++ot){
    f32x4 d2 = {0.f,0.f,0.f,0.f};
#pragma unroll
    for (int t=0;t<4;++t){
      h4 f = *(const h4*)(W2s + (size_t)((ot*16 + 4*w + t)*64 + lane)*4);
      d2 = __builtin_amdgcn_mfma_f32_16x16x16f16(f, hidB[t], d2, 0,0,0);
    }
#pragma unroll
    for (int r=0;r<4;++r) part[w][ot][4*g+r][c] = d2[r];
  }
  __syncthreads();

#pragma unroll
  for (int i=tid;i<1024;i+=256){
    int n = i>>7, col = i&127;
    int ot = col>>4, m = col&15;
    float v = part[0][ot][m][n] + part[1][ot][m][n]
            + part[2][ot][m][n] + part[3][ot][m][n];
    out[(size_t)(n0+n)*DOUTC + col] = hrow[n][col] + v + bb2[col];
  }
}

extern "C" void kernel_launch(void* const* d_in, const int* in_sizes, int n_in,
                              void* d_out, int out_size, void* d_ws, size_t ws_size,
                              hipStream_t stream)
{
  const float* x     = (const float*)d_in[0];
  const int*   adj   = (const int*)  d_in[1];
  const float* ea    = (const float*)d_in[2];
  const float* ln1_g = (const float*)d_in[3];
  const float* ln1_b = (const float*)d_in[4];
  const float* Wp    = (const float*)d_in[5];
  const float* bp    = (const float*)d_in[6];
  const float* eln_g = (const float*)d_in[7];
  const float* eln_b = (const float*)d_in[8];
  const float* We1   = (const float*)d_in[9];
  const float* be1   = (const float*)d_in[10];
  const float* We2   = (const float*)d_in[11];
  const float* be2   = (const float*)d_in[12];
  const float* Wq    = (const float*)d_in[13];
  const float* Wk    = (const float*)d_in[14];
  const float* Wv    = (const float*)d_in[15];
  const float* ffW1  = (const float*)d_in[16];
  const float* ffb1  = (const float*)d_in[17];
  const float* ffW2  = (const float*)d_in[18];
  const float* ffb2  = (const float*)d_in[19];
  const float* ln2_g = (const float*)d_in[20];
  const float* ln2_b = (const float*)d_in[21];
  float* out = (float*)d_out;

  char* ws = (char*)d_ws;
  float*    xp  = (float*)(ws);                       // 2MB (f32)
  float*    ctx = (float*)(ws + ((size_t)2<<20));     // 2MB
  _Float16* Qh  = (_Float16*)(ws + ((size_t)4<<20));  // 1MB
  _Float16* Kh  = (_Float16*)(ws + ((size_t)5<<20));  // 1MB
  _Float16* Vh  = (_Float16*)(ws + ((size_t)6<<20));  // 1MB
  _Float16* ebf = (_Float16*)(ws + ((size_t)7<<20));  // 32MB [B,H,N,N] f16
  char* wsw = ws + ((size_t)39<<20);                  // swizzled weights (258KB)
  _Float16* W1s = (_Float16*)(wsw);                   // 64KB
  _Float16* W2s = (_Float16*)(wsw + 65536);           // 64KB
  _Float16* Wps = (_Float16*)(wsw + 131072);          // 32KB
  _Float16* Wqs = (_Float16*)(wsw + 163840);          // 32KB
  _Float16* Wks = (_Float16*)(wsw + 196608);          // 32KB
  _Float16* Wvs = (_Float16*)(wsw + 229376);          // 32KB
  _Float16* Wes = (_Float16*)(wsw + 262144);          // 2KB

  k_prep<<<516, 256, 0, stream>>>(Wp, Wq, Wk, Wv, ffW1, ffW2, We1, We2,
                                  Wps, Wqs, Wks, Wvs, W1s, W2s, Wes);
  k_proj<<<(BB*NN)/16, 256, 0, stream>>>(x, ln1_g, ln1_b, Wps, bp, Wqs, Wks, Wvs, xp, Qh, Kh, Vh);
  k_edge<<<BB*NN, 256, 0, stream>>>(ea, adj, eln_g, eln_b, Wes, be1, be2, ebf);
  k_attn<<<BB*HHC*8, 256, 0, stream>>>(Qh, Kh, Vh, ebf, ctx);
  k_ffn<<<(BB*NN)/8, 256, 0, stream>>>(xp, ctx, ln2_g, ln2_b, W1s, ffb1, W2s, ffb2, out);
}